// Round 1
// baseline (50.194 us; speedup 1.0000x reference)
//
#include <hip/hip_runtime.h>

#define IN_F    4096
#define OUT_F   11008
#define NGROUP  512        // IN_F / 8
#define CHUNK   16         // groups per thread per block
#define NCHUNK  (NGROUP / CHUNK)   // 32
#define OTILES  (OUT_F / 256)      // 43
#define BATCH   4

// out[b][o] = bias[o]
__global__ __launch_bounds__(256) void init_out_kernel(
    const float* __restrict__ bias, float* __restrict__ out)
{
    const int o = blockIdx.x * 256 + threadIdx.x;          // 43*256 = 11008 exactly
    out[(size_t)blockIdx.y * OUT_F + o] = bias[o];
}

// Each thread: one output o, CHUNK consecutive groups starting at g0.
__global__ __launch_bounds__(256) void aqlm_kernel(
    const float* __restrict__ x,        // [4][4096]
    const float* __restrict__ cb,       // [65536][8]
    const int*   __restrict__ codes,    // [11008][512]
    const float* __restrict__ scales,   // [11008]
    float*       __restrict__ out)      // [4][11008]
{
    const int o  = blockIdx.x * 256 + threadIdx.x;
    const int g0 = blockIdx.y * CHUNK;

    // Preload this lane's 16 codes: exactly one fully-used 64-B cache line.
    int code[CHUNK];
    const int4* cp = (const int4*)(codes + (size_t)o * NGROUP + g0);
#pragma unroll
    for (int j = 0; j < CHUNK / 4; ++j) {
        const int4 c = cp[j];
        code[4 * j + 0] = c.x;
        code[4 * j + 1] = c.y;
        code[4 * j + 2] = c.z;
        code[4 * j + 3] = c.w;
    }

    float acc[BATCH];
#pragma unroll
    for (int b = 0; b < BATCH; ++b) acc[b] = 0.f;

#pragma unroll 4
    for (int j = 0; j < CHUNK; ++j) {
        // Random 32-B gather from the 2 MB codebook (L2-resident).
        const float4* e = (const float4*)(cb + (size_t)(unsigned)code[j] * 8u);
        const float4 w0 = e[0];
        const float4 w1 = e[1];
        // x slice for group g: wave-uniform address -> scalar loads.
        const float* xg = x + (size_t)(g0 + j) * 8;
#pragma unroll
        for (int b = 0; b < BATCH; ++b) {
            const float* xb = xg + b * IN_F;
            acc[b] += xb[0] * w0.x + xb[1] * w0.y + xb[2] * w0.z + xb[3] * w0.w
                    + xb[4] * w1.x + xb[5] * w1.y + xb[6] * w1.z + xb[7] * w1.w;
        }
    }

    const float s = scales[o];
    atomicAdd(out + 0 * (size_t)OUT_F + o, s * acc[0]);
    atomicAdd(out + 1 * (size_t)OUT_F + o, s * acc[1]);
    atomicAdd(out + 2 * (size_t)OUT_F + o, s * acc[2]);
    atomicAdd(out + 3 * (size_t)OUT_F + o, s * acc[3]);
}

extern "C" void kernel_launch(void* const* d_in, const int* in_sizes, int n_in,
                              void* d_out, int out_size, void* d_ws, size_t ws_size,
                              hipStream_t stream) {
    const float* x      = (const float*)d_in[0];   // (4, 4096)
    const float* cb     = (const float*)d_in[1];   // (1, 65536, 1, 8)
    const int*   codes  = (const int*)d_in[2];     // (11008, 512, 1)
    const float* scales = (const float*)d_in[3];   // (11008, 1, 1, 1)
    const float* bias   = (const float*)d_in[4];   // (11008,)
    float* out = (float*)d_out;                    // (4, 11008)

    hipLaunchKernelGGL(init_out_kernel, dim3(OTILES, BATCH), dim3(256), 0, stream,
                       bias, out);
    hipLaunchKernelGGL(aqlm_kernel, dim3(OTILES, NCHUNK), dim3(256), 0, stream,
                       x, cb, codes, scales, out);
}